// Round 3
// baseline (361.488 us; speedup 1.0000x reference)
//
#include <hip/hip_runtime.h>
#include <math.h>

// Problem dims (fixed by reference setup_inputs)
#define B_  8
#define D_  128
#define H_  256
#define W_  256
#define NACC 9      // S, SW, SW2, SD, SD2, SH, SH2, LEFT, CENT
#define NPART 256   // stage-1 blocks per batch

// central box bounds (D//3, 2D//3, etc.)
#define D1 42
#define D2 85
#define H1 85
#define H2 170
#define W1 85
#define W2 170

__device__ __forceinline__ float waveSum(float x) {
    x += __shfl_down(x, 32, 64);
    x += __shfl_down(x, 16, 64);
    x += __shfl_down(x,  8, 64);
    x += __shfl_down(x,  4, 64);
    x += __shfl_down(x,  2, 64);
    x += __shfl_down(x,  1, 64);
    return x;
}

// Stage 1 streaming reduction.
// R1 lesson: no atomics (73728 contended RMWs cost ~550us).
// R2 lesson: one load in flight per wave -> ~2.3 TB/s. Fix: each wave owns
// a CONTIGUOUS 4-row (4 KiB) span per group and issues 4 independent
// global_load_dwordx4 before consuming any -> 4x memory-level parallelism,
// better DRAM page locality. 8 static groups/wave, stride 4096 rows.
__global__ __launch_bounds__(256) void mfe_reduce(const float* __restrict__ in,
                                                  float* __restrict__ part) {
    const int b    = blockIdx.y;
    const int tid  = threadIdx.x;
    const int lane = tid & 63;
    const int wave = tid >> 6;
    const int gwave = blockIdx.x * 4 + wave;         // 0..1023

    const float* __restrict__ base = in + (size_t)b * (D_ * H_ * W_);

    // per-lane constants (w dimension)
    const int   w0  = lane * 4;
    const float fw0 = (float)(w0 + 0), fw1 = (float)(w0 + 1);
    const float fw2 = (float)(w0 + 2), fw3 = (float)(w0 + 3);
    const float q0 = fw0 * fw0, q1 = fw1 * fw1, q2 = fw2 * fw2, q3 = fw3 * fw3;
    const float cm0 = (w0 + 0 >= W1 && w0 + 0 < W2) ? 1.f : 0.f;
    const float cm1 = (w0 + 1 >= W1 && w0 + 1 < W2) ? 1.f : 0.f;
    const float cm2 = (w0 + 2 >= W1 && w0 + 2 < W2) ? 1.f : 0.f;
    const float cm3 = (w0 + 3 >= W1 && w0 + 3 < W2) ? 1.f : 0.f;
    const float lf  = (w0 < (W_ / 2)) ? 1.f : 0.f;   // lanes 0..31 cover w<128

    float aS = 0.f, aSW = 0.f, aSW2 = 0.f;
    float aSD = 0.f, aSD2 = 0.f, aSH = 0.f, aSH2 = 0.f;
    float aL = 0.f, aC = 0.f;

    // 32768 rows/batch, 1024 waves/batch, 4 consecutive rows per group,
    // 8 groups per wave.
    for (int g = 0; g < 8; ++g) {
        const int row0 = (gwave << 2) + (g << 12);   // 4*gwave + 4096*g
        const float* r = base + (size_t)row0 * W_ + w0;

        // 4 independent 16B loads in flight before any use
        const float4 p0 = *(const float4*)(r);
        const float4 p1 = *(const float4*)(r + W_);
        const float4 p2 = *(const float4*)(r + 2 * W_);
        const float4 p3 = *(const float4*)(r + 3 * W_);

        const int d  = row0 >> 8;                    // same d for all 4 rows
        const int h0 = row0 & (H_ - 1);              // h0, h0+1, h0+2, h0+3
        const float fd = (float)d;
        const bool dhit = (d >= D1 && d < D2);

#pragma unroll
        for (int j = 0; j < 4; ++j) {
            const float4 p = (j == 0) ? p0 : (j == 1) ? p1 : (j == 2) ? p2 : p3;
            const int   h  = h0 + j;
            const float fh = (float)h;

            const float s   = (p.x + p.y) + (p.z + p.w);
            const float sw  = fmaf(fw0, p.x, fmaf(fw1, p.y, fmaf(fw2, p.z, fw3 * p.w)));
            const float sw2 = fmaf(q0,  p.x, fmaf(q1,  p.y, fmaf(q2,  p.z, q3  * p.w)));
            const float cs  = fmaf(cm0, p.x, fmaf(cm1, p.y, fmaf(cm2, p.z, cm3 * p.w)));
            const float inbox = (dhit && h >= H1 && h < H2) ? 1.f : 0.f;

            aS   += s;
            aSW  += sw;
            aSW2 += sw2;
            aSD   = fmaf(fd,      s,  aSD);
            aSD2  = fmaf(fd * fd, s,  aSD2);
            aSH   = fmaf(fh,      s,  aSH);
            aSH2  = fmaf(fh * fh, s,  aSH2);
            aL    = fmaf(lf,      s,  aL);
            aC    = fmaf(inbox,   cs, aC);
        }
    }

    aS   = waveSum(aS);
    aSW  = waveSum(aSW);
    aSW2 = waveSum(aSW2);
    aSD  = waveSum(aSD);
    aSD2 = waveSum(aSD2);
    aSH  = waveSum(aSH);
    aSH2 = waveSum(aSH2);
    aL   = waveSum(aL);
    aC   = waveSum(aC);

    __shared__ float lds[4 * NACC];
    if (lane == 0) {
        float* l = lds + wave * NACC;
        l[0] = aS;  l[1] = aSW;  l[2] = aSW2;
        l[3] = aSD; l[4] = aSD2; l[5] = aSH; l[6] = aSH2;
        l[7] = aL;  l[8] = aC;
    }
    __syncthreads();
    if (tid < NACC) {
        const float v = lds[0 * NACC + tid] + lds[1 * NACC + tid]
                      + lds[2 * NACC + tid] + lds[3 * NACC + tid];
        part[((size_t)b * NPART + blockIdx.x) * NACC + tid] = v;
    }
}

// Stage 2: one wave per batch reduces NPART partial vectors and emits the
// 4 features.
__global__ __launch_bounds__(64) void mfe_final(const float* __restrict__ part,
                                                float* __restrict__ out) {
    const int b    = blockIdx.x;
    const int lane = threadIdx.x;
    const float* __restrict__ p = part + (size_t)b * NPART * NACC;

    float a[NACC];
#pragma unroll
    for (int k = 0; k < NACC; ++k) a[k] = 0.f;
    for (int r = lane; r < NPART; r += 64) {
#pragma unroll
        for (int k = 0; k < NACC; ++k) a[k] += p[r * NACC + k];
    }
#pragma unroll
    for (int k = 0; k < NACC; ++k) a[k] = waveSum(a[k]);

    if (lane == 0) {
        const float S = a[0], SW = a[1], SW2 = a[2];
        const float SD = a[3], SD2 = a[4], SH = a[5], SH2 = a[6];
        const float L = a[7], C = a[8];

        const float total = fmaxf(S, 1e-6f);
        const float md = SD / total, mh = SH / total, mw = SW / total;
        const float vd = SD2 / total - md * md;
        const float vh = SH2 / total - mh * mh;
        const float vw = SW2 / total - mw * mw;
        const float v  = fmaxf(fmaxf(fmaxf(vd, vh), vw), 0.f);

        const float diam_norm = fminf(fmaxf(2.f * sqrtf(v) * (1.0f / 100.0f), 0.f), 1.f);

        const float SPHERE_VOL = (4.0f / 3.0f) * 3.14159f * 1000.0f;   // 4188.78667
        const float count_norm = fminf(fmaxf(S / SPHERE_VOL, 0.f), 5.f) * (1.0f / 5.0f);

        const float vasc = fminf(fmaxf(C / total, 0.f), 1.f);

        const float R  = S - L;
        const float mn = fminf(L, R);
        const float mx = fmaxf(fmaxf(L, R), 1e-6f);
        const float lobe = fminf(fmaxf(mn / mx, 0.f), 1.f);

        out[b * 4 + 0] = diam_norm;
        out[b * 4 + 1] = count_norm;
        out[b * 4 + 2] = vasc;
        out[b * 4 + 3] = lobe;
    }
}

extern "C" void kernel_launch(void* const* d_in, const int* in_sizes, int n_in,
                              void* d_out, int out_size, void* d_ws, size_t ws_size,
                              hipStream_t stream) {
    const float* in   = (const float*)d_in[0];
    float*       out  = (float*)d_out;
    float*       part = (float*)d_ws;   // B_*NPART*NACC floats = 72 KB, fully
                                        // overwritten every launch (no memset).

    dim3 grid(NPART, B_);               // 2048 blocks, 8192 waves
    mfe_reduce<<<grid, 256, 0, stream>>>(in, part);
    mfe_final<<<B_, 64, 0, stream>>>(part, out);
}

// Round 4
// 331.645 us; speedup vs baseline: 1.0900x; 1.0900x over previous
//
#include <hip/hip_runtime.h>
#include <math.h>

// Problem dims (fixed by reference setup_inputs)
#define B_  8
#define D_  128
#define H_  256
#define W_  256
#define NACC 9      // S, SW, SW2, SD, SD2, SH, SH2, LEFT, CENT
#define NPART 256   // stage-1 blocks per batch

// central box bounds (D//3, 2D//3, etc.)
#define D1 42
#define D2 85
#define H1 85
#define H2 170
#define W1 85
#define W2 170

typedef float f32x4 __attribute__((ext_vector_type(4)));

__device__ __forceinline__ float waveSum(float x) {
    x += __shfl_down(x, 32, 64);
    x += __shfl_down(x, 16, 64);
    x += __shfl_down(x,  8, 64);
    x += __shfl_down(x,  4, 64);
    x += __shfl_down(x,  2, 64);
    x += __shfl_down(x,  1, 64);
    return x;
}

// Stage 1 streaming reduction.
// R1 lesson: no atomics (73728 contended RMWs cost ~550us serialized).
// R3 lesson: NOT latency-bound (4x MLP was neutral). Theory: the harness's
// 1 GiB 0xAA ws-poison fill leaves LLC full of dirty lines; every read miss
// forces a dirty-line writeback -> ~524 MB mixed R/W traffic instead of
// 268 MB pure reads. Fix: NON-TEMPORAL loads (no-allocate) -> no evictions,
// input is single-use so caching it is worthless anyway.
__global__ __launch_bounds__(256) void mfe_reduce(const float* __restrict__ in,
                                                  float* __restrict__ part) {
    const int b    = blockIdx.y;
    const int tid  = threadIdx.x;
    const int lane = tid & 63;
    const int wave = tid >> 6;
    const int gwave = blockIdx.x * 4 + wave;         // 0..1023

    const float* __restrict__ base = in + (size_t)b * (D_ * H_ * W_);

    // per-lane constants (w dimension)
    const int   w0  = lane * 4;
    const float fw0 = (float)(w0 + 0), fw1 = (float)(w0 + 1);
    const float fw2 = (float)(w0 + 2), fw3 = (float)(w0 + 3);
    const float q0 = fw0 * fw0, q1 = fw1 * fw1, q2 = fw2 * fw2, q3 = fw3 * fw3;
    const float cm0 = (w0 + 0 >= W1 && w0 + 0 < W2) ? 1.f : 0.f;
    const float cm1 = (w0 + 1 >= W1 && w0 + 1 < W2) ? 1.f : 0.f;
    const float cm2 = (w0 + 2 >= W1 && w0 + 2 < W2) ? 1.f : 0.f;
    const float cm3 = (w0 + 3 >= W1 && w0 + 3 < W2) ? 1.f : 0.f;
    const float lf  = (w0 < (W_ / 2)) ? 1.f : 0.f;   // lanes 0..31 cover w<128

    float aS = 0.f, aSW = 0.f, aSW2 = 0.f;
    float aSD = 0.f, aSD2 = 0.f, aSH = 0.f, aSH2 = 0.f;
    float aL = 0.f, aC = 0.f;

    // 32768 rows/batch, 1024 waves/batch, 4 consecutive rows per group,
    // 8 groups per wave (stride 4096 rows between groups).
    for (int g = 0; g < 8; ++g) {
        const int row0 = (gwave << 2) + (g << 12);   // 4*gwave + 4096*g
        const float* r = base + (size_t)row0 * W_ + w0;

        // 4 independent 16B non-temporal loads in flight before any use
        const f32x4 p0 = __builtin_nontemporal_load((const f32x4*)(r));
        const f32x4 p1 = __builtin_nontemporal_load((const f32x4*)(r + W_));
        const f32x4 p2 = __builtin_nontemporal_load((const f32x4*)(r + 2 * W_));
        const f32x4 p3 = __builtin_nontemporal_load((const f32x4*)(r + 3 * W_));

        const int d  = row0 >> 8;                    // same d for all 4 rows
        const int h0 = row0 & (H_ - 1);              // h0, h0+1, h0+2, h0+3
        const float fd = (float)d;
        const bool dhit = (d >= D1 && d < D2);

#pragma unroll
        for (int j = 0; j < 4; ++j) {
            const f32x4 p = (j == 0) ? p0 : (j == 1) ? p1 : (j == 2) ? p2 : p3;
            const int   h  = h0 + j;
            const float fh = (float)h;

            const float s   = (p[0] + p[1]) + (p[2] + p[3]);
            const float sw  = fmaf(fw0, p[0], fmaf(fw1, p[1], fmaf(fw2, p[2], fw3 * p[3])));
            const float sw2 = fmaf(q0,  p[0], fmaf(q1,  p[1], fmaf(q2,  p[2], q3  * p[3])));
            const float cs  = fmaf(cm0, p[0], fmaf(cm1, p[1], fmaf(cm2, p[2], cm3 * p[3])));
            const float inbox = (dhit && h >= H1 && h < H2) ? 1.f : 0.f;

            aS   += s;
            aSW  += sw;
            aSW2 += sw2;
            aSD   = fmaf(fd,      s,  aSD);
            aSD2  = fmaf(fd * fd, s,  aSD2);
            aSH   = fmaf(fh,      s,  aSH);
            aSH2  = fmaf(fh * fh, s,  aSH2);
            aL    = fmaf(lf,      s,  aL);
            aC    = fmaf(inbox,   cs, aC);
        }
    }

    aS   = waveSum(aS);
    aSW  = waveSum(aSW);
    aSW2 = waveSum(aSW2);
    aSD  = waveSum(aSD);
    aSD2 = waveSum(aSD2);
    aSH  = waveSum(aSH);
    aSH2 = waveSum(aSH2);
    aL   = waveSum(aL);
    aC   = waveSum(aC);

    __shared__ float lds[4 * NACC];
    if (lane == 0) {
        float* l = lds + wave * NACC;
        l[0] = aS;  l[1] = aSW;  l[2] = aSW2;
        l[3] = aSD; l[4] = aSD2; l[5] = aSH; l[6] = aSH2;
        l[7] = aL;  l[8] = aC;
    }
    __syncthreads();
    if (tid < NACC) {
        const float v = lds[0 * NACC + tid] + lds[1 * NACC + tid]
                      + lds[2 * NACC + tid] + lds[3 * NACC + tid];
        part[((size_t)b * NPART + blockIdx.x) * NACC + tid] = v;
    }
}

// Stage 2: one wave per batch reduces NPART partial vectors and emits the
// 4 features.
__global__ __launch_bounds__(64) void mfe_final(const float* __restrict__ part,
                                                float* __restrict__ out) {
    const int b    = blockIdx.x;
    const int lane = threadIdx.x;
    const float* __restrict__ p = part + (size_t)b * NPART * NACC;

    float a[NACC];
#pragma unroll
    for (int k = 0; k < NACC; ++k) a[k] = 0.f;
    for (int r = lane; r < NPART; r += 64) {
#pragma unroll
        for (int k = 0; k < NACC; ++k) a[k] += p[r * NACC + k];
    }
#pragma unroll
    for (int k = 0; k < NACC; ++k) a[k] = waveSum(a[k]);

    if (lane == 0) {
        const float S = a[0], SW = a[1], SW2 = a[2];
        const float SD = a[3], SD2 = a[4], SH = a[5], SH2 = a[6];
        const float L = a[7], C = a[8];

        const float total = fmaxf(S, 1e-6f);
        const float md = SD / total, mh = SH / total, mw = SW / total;
        const float vd = SD2 / total - md * md;
        const float vh = SH2 / total - mh * mh;
        const float vw = SW2 / total - mw * mw;
        const float v  = fmaxf(fmaxf(fmaxf(vd, vh), vw), 0.f);

        const float diam_norm = fminf(fmaxf(2.f * sqrtf(v) * (1.0f / 100.0f), 0.f), 1.f);

        const float SPHERE_VOL = (4.0f / 3.0f) * 3.14159f * 1000.0f;   // 4188.78667
        const float count_norm = fminf(fmaxf(S / SPHERE_VOL, 0.f), 5.f) * (1.0f / 5.0f);

        const float vasc = fminf(fmaxf(C / total, 0.f), 1.f);

        const float R  = S - L;
        const float mn = fminf(L, R);
        const float mx = fmaxf(fmaxf(L, R), 1e-6f);
        const float lobe = fminf(fmaxf(mn / mx, 0.f), 1.f);

        out[b * 4 + 0] = diam_norm;
        out[b * 4 + 1] = count_norm;
        out[b * 4 + 2] = vasc;
        out[b * 4 + 3] = lobe;
    }
}

extern "C" void kernel_launch(void* const* d_in, const int* in_sizes, int n_in,
                              void* d_out, int out_size, void* d_ws, size_t ws_size,
                              hipStream_t stream) {
    const float* in   = (const float*)d_in[0];
    float*       out  = (float*)d_out;
    float*       part = (float*)d_ws;   // B_*NPART*NACC floats = 72 KB, fully
                                        // overwritten every launch (no memset).

    dim3 grid(NPART, B_);               // 2048 blocks, 8192 waves
    mfe_reduce<<<grid, 256, 0, stream>>>(in, part);
    mfe_final<<<B_, 64, 0, stream>>>(part, out);
}